// Round 17
// baseline (120.256 us; speedup 1.0000x reference)
//
#include <hip/hip_runtime.h>

#define EPS 1e-6f

constexpr int C    = 128;
constexpr int HW   = 65536;    // 256*256
constexpr int TILE = 128;      // pixels per block
constexpr int NT   = 512;      // 8 waves

typedef __attribute__((ext_vector_type(8))) short bf16x8;
typedef __attribute__((ext_vector_type(4))) float f32x4;

__device__ __forceinline__ unsigned short f2bf(float f) {   // RNE
    unsigned u = __float_as_uint(f);
    u += 0x7fff + ((u >> 16) & 1);
    return (unsigned short)(u >> 16);
}
__device__ __forceinline__ float bf2f(unsigned short u) {
    return __uint_as_float(((unsigned)u) << 16);
}
__device__ __forceinline__ unsigned pack2(float lo, float hi) {
    return (unsigned)f2bf(lo) | ((unsigned)f2bf(hi) << 16);
}

__global__ __launch_bounds__(NT, 4) void spnorm_kernel(
    const float* __restrict__ x, const float* __restrict__ W,
    const float* __restrict__ bias, float* __restrict__ out)
{
    // bufT[p][c]: normalized bf16, transposed, XOR-swizzled (byte ^= (p&15)<<4)
    __shared__ unsigned short bufT[C * TILE];              // 32 KB
    __shared__ float red1[4][TILE], red2[4][TILE];         // 4 KB
    __shared__ float u_s[TILE], se_s[TILE];                // 1 KB

    const int tid = threadIdx.x;
    const int l   = tid & 63;
    const int wv  = tid >> 6;
    const int batch = blockIdx.x >> 9;                     // 512 blocks per image
    const int hw0   = (blockIdx.x & 511) * TILE;
    const int base  = batch * (C * HW) + hw0;

    const int p = tid & 127;                               // pixel
    const int q = tid >> 7;                                // channel group (32 ch)

    // ---- Phase 1: x straight into registers, channel-strided, coalesced across p ----
    float v[32];
    {
        const float* xp = x + base + q * 32 * HW + p;
        #pragma unroll
        for (int i = 0; i < 32; ++i)
            v[i] = xp[i * HW];
    }

    // ---- W-fragments (fp32 -> bf16) from global; B operand of the swapped MFMA ----
    const int arow  = (wv << 4) + (l & 15);                // this lane's output channel row
    const int acol0 = (l >> 4) << 3;
    bf16x8 wfrag[4];
    #pragma unroll
    for (int kk = 0; kk < 4; ++kk) {
        const float* wp = W + arow * C + kk * 32 + acol0;
        float4 wa = *reinterpret_cast<const float4*>(wp);
        float4 wb = *reinterpret_cast<const float4*>(wp + 4);
        bf16x8 f;
        f[0] = (short)f2bf(wa.x); f[1] = (short)f2bf(wa.y);
        f[2] = (short)f2bf(wa.z); f[3] = (short)f2bf(wa.w);
        f[4] = (short)f2bf(wb.x); f[5] = (short)f2bf(wb.y);
        f[6] = (short)f2bf(wb.z); f[7] = (short)f2bf(wb.w);
        wfrag[kk] = f;
    }

    // ---- Phase 2: partial sums -> LDS ----
    {
        float s1 = 0.f, s2 = 0.f;
        #pragma unroll
        for (int i = 0; i < 32; ++i) {
            s1 += v[i];
            s2 = fmaf(v[i], v[i], s2);
        }
        red1[q][p] = s1;
        red2[q][p] = s2;
    }

    // Pin v[]: prevents reload-rematerialization across the barrier.
    #pragma unroll
    for (int i = 0; i < 32; ++i) asm volatile("" : "+v"(v[i]));

    __syncthreads();

    // ---- Phase 3: every thread finalizes (redundant x4), normalizes, writes bufT ----
    {
        float s1 = red1[0][p] + red1[1][p] + red1[2][p] + red1[3][p];
        float s2 = red2[0][p] + red2[1][p] + red2[2][p] + red2[3][p];
        float u   = s1 * (1.0f / 128.0f);
        float var = fmaxf((s2 - s1 * u) * (1.0f / 127.0f), 0.0f);
        float se  = sqrtf(var) + EPS;
        float iv  = 1.0f / se;
        if (q == 0) {                       // wave-uniform branch (tid < 128)
            u_s[p]  = u;
            se_s[p] = se;
        }
        char* tb = (char*)bufT;
        const int rowoff = p * 256;         // 128 ushort per row
        const int swz    = (p & 15) << 4;
        #pragma unroll
        for (int o8 = 0; o8 < 4; ++o8) {
            float n0 = (v[o8 * 8 + 0] - u) * iv;
            float n1 = (v[o8 * 8 + 1] - u) * iv;
            float n2 = (v[o8 * 8 + 2] - u) * iv;
            float n3 = (v[o8 * 8 + 3] - u) * iv;
            float n4 = (v[o8 * 8 + 4] - u) * iv;
            float n5 = (v[o8 * 8 + 5] - u) * iv;
            float n6 = (v[o8 * 8 + 6] - u) * iv;
            float n7 = (v[o8 * 8 + 7] - u) * iv;
            uint4 d;
            d.x = pack2(n0, n1);
            d.y = pack2(n2, n3);
            d.z = pack2(n4, n5);
            d.w = pack2(n6, n7);
            int byte = (rowoff + (q * 4 + o8) * 16) ^ swz;
            *reinterpret_cast<uint4*>(tb + byte) = d;
        }
    }
    __syncthreads();

    // ---- Phase 4: SWAPPED-operand MFMA: D[px][och] = mfma(A = n-x tile, B = W).
    //      Lane ends with 4 CONSECUTIVE PIXELS of ONE channel -> plain float4 store
    //      (A/B vs round 16: nt OFF, everything else identical). ----
    {
        const char* tb = (const char*)bufT;
        const int och  = (wv << 4) + (l & 15);      // lane's output channel
        const int prow = (l >> 4) << 2;             // px sub-row 0,4,8,12
        const int koff = (l >> 4) << 4;             // k-octet byte offset for A-read
        const float bb = bias[och];
        float* outp = out + base;
        #pragma unroll
        for (int pt = 0; pt < 8; ++pt) {
            const int ar   = (pt << 4) + (l & 15);
            const int aoff = ar * 256;
            const int aswz = (ar & 15) << 4;
            f32x4 acc = { bb, bb, bb, bb };
            #pragma unroll
            for (int kk = 0; kk < 4; ++kk) {
                int byte = (aoff + kk * 64 + koff) ^ aswz;
                bf16x8 afr = *reinterpret_cast<const bf16x8*>(tb + byte);
                acc = __builtin_amdgcn_mfma_f32_16x16x32_bf16(afr, wfrag[kk], acc, 0, 0, 0);
            }
            const int px0 = (pt << 4) + prow;       // 4 consecutive pixels
            float4 u4  = *reinterpret_cast<const float4*>(&u_s[px0]);
            float4 se4 = *reinterpret_cast<const float4*>(&se_s[px0]);
            float xr0, xr1, xr2, xr3;
            {
                int r0 = px0 + 0, r1 = px0 + 1, r2 = px0 + 2, r3 = px0 + 3;
                xr0 = bf2f(*reinterpret_cast<const unsigned short*>(tb + ((r0 * 256 + och * 2) ^ ((r0 & 15) << 4))));
                xr1 = bf2f(*reinterpret_cast<const unsigned short*>(tb + ((r1 * 256 + och * 2) ^ ((r1 & 15) << 4))));
                xr2 = bf2f(*reinterpret_cast<const unsigned short*>(tb + ((r2 * 256 + och * 2) ^ ((r2 & 15) << 4))));
                xr3 = bf2f(*reinterpret_cast<const unsigned short*>(tb + ((r3 * 256 + och * 2) ^ ((r3 & 15) << 4))));
            }
            float4 o4;
            o4.x = fmaf(xr0, se4.x, u4.x) * acc[0];
            o4.y = fmaf(xr1, se4.y, u4.y) * acc[1];
            o4.z = fmaf(xr2, se4.z, u4.z) * acc[2];
            o4.w = fmaf(xr3, se4.w, u4.w) * acc[3];
            *reinterpret_cast<float4*>(outp + och * HW + px0) = o4;
        }
    }
}

extern "C" void kernel_launch(void* const* d_in, const int* in_sizes, int n_in,
                              void* d_out, int out_size, void* d_ws, size_t ws_size,
                              hipStream_t stream) {
    const float* x = (const float*)d_in[0];
    const float* W = (const float*)d_in[1];
    const float* b = (const float*)d_in[2];
    float* out     = (float*)d_out;

    const int nblk = 8 * HW / TILE;            // 4096 blocks
    spnorm_kernel<<<nblk, NT, 0, stream>>>(x, W, b, out);
}

// Round 18
// 106.954 us; speedup vs baseline: 1.1244x; 1.1244x over previous
//
#include <hip/hip_runtime.h>

#define EPS 1e-6f

constexpr int C    = 128;
constexpr int HW   = 65536;    // 256*256
constexpr int TILE = 128;      // pixels per block
constexpr int NT   = 512;      // 8 waves

typedef __attribute__((ext_vector_type(8))) short bf16x8;
typedef __attribute__((ext_vector_type(4))) float f32x4;

__device__ __forceinline__ unsigned short f2bf(float f) {   // RNE
    unsigned u = __float_as_uint(f);
    u += 0x7fff + ((u >> 16) & 1);
    return (unsigned short)(u >> 16);
}
__device__ __forceinline__ float bf2f(unsigned short u) {
    return __uint_as_float(((unsigned)u) << 16);
}
__device__ __forceinline__ unsigned pack2(float lo, float hi) {
    return (unsigned)f2bf(lo) | ((unsigned)f2bf(hi) << 16);
}

__global__ __launch_bounds__(NT, 4) void spnorm_kernel(
    const float* __restrict__ x, const float* __restrict__ W,
    const float* __restrict__ bias, float* __restrict__ out)
{
    // bufT[p][c]: normalized bf16, transposed, XOR-swizzled (byte ^= (p&15)<<4)
    __shared__ unsigned short bufT[C * TILE];              // 32 KB
    __shared__ float red1[4][TILE], red2[4][TILE];         // 4 KB
    __shared__ float u_s[TILE], se_s[TILE];                // 1 KB

    const int tid = threadIdx.x;
    const int l   = tid & 63;
    const int wv  = tid >> 6;
    const int batch = blockIdx.x >> 9;                     // 512 blocks per image
    const int hw0   = (blockIdx.x & 511) * TILE;
    const int base  = batch * (C * HW) + hw0;

    const int p = tid & 127;                               // pixel
    const int q = tid >> 7;                                // channel group (32 ch)

    // ---- Phase 1: x straight into registers, channel-strided, coalesced across p ----
    float v[32];
    {
        const float* xp = x + base + q * 32 * HW + p;
        #pragma unroll
        for (int i = 0; i < 32; ++i)
            v[i] = xp[i * HW];
    }

    // ---- W-fragments (fp32 -> bf16) from global; B operand of the swapped MFMA ----
    const int arow  = (wv << 4) + (l & 15);                // this lane's output channel row
    const int acol0 = (l >> 4) << 3;
    bf16x8 wfrag[4];
    #pragma unroll
    for (int kk = 0; kk < 4; ++kk) {
        const float* wp = W + arow * C + kk * 32 + acol0;
        float4 wa = *reinterpret_cast<const float4*>(wp);
        float4 wb = *reinterpret_cast<const float4*>(wp + 4);
        bf16x8 f;
        f[0] = (short)f2bf(wa.x); f[1] = (short)f2bf(wa.y);
        f[2] = (short)f2bf(wa.z); f[3] = (short)f2bf(wa.w);
        f[4] = (short)f2bf(wb.x); f[5] = (short)f2bf(wb.y);
        f[6] = (short)f2bf(wb.z); f[7] = (short)f2bf(wb.w);
        wfrag[kk] = f;
    }

    // ---- Phase 2: partial sums -> LDS ----
    {
        float s1 = 0.f, s2 = 0.f;
        #pragma unroll
        for (int i = 0; i < 32; ++i) {
            s1 += v[i];
            s2 = fmaf(v[i], v[i], s2);
        }
        red1[q][p] = s1;
        red2[q][p] = s2;
    }

    // Pin v[]: prevents reload-rematerialization across the barrier (rounds 8/10:
    // VGPR_Count=32 => compiler re-loads x in phase 3).
    #pragma unroll
    for (int i = 0; i < 32; ++i) asm volatile("" : "+v"(v[i]));

    __syncthreads();

    // ---- Phase 3: every thread finalizes (redundant x4), normalizes, writes bufT ----
    {
        float s1 = red1[0][p] + red1[1][p] + red1[2][p] + red1[3][p];
        float s2 = red2[0][p] + red2[1][p] + red2[2][p] + red2[3][p];
        float u   = s1 * (1.0f / 128.0f);
        float var = fmaxf((s2 - s1 * u) * (1.0f / 127.0f), 0.0f);
        float se  = sqrtf(var) + EPS;
        float iv  = 1.0f / se;
        if (q == 0) {                       // wave-uniform branch (tid < 128)
            u_s[p]  = u;
            se_s[p] = se;
        }
        char* tb = (char*)bufT;
        const int rowoff = p * 256;         // 128 ushort per row
        const int swz    = (p & 15) << 4;
        #pragma unroll
        for (int o8 = 0; o8 < 4; ++o8) {
            float n0 = (v[o8 * 8 + 0] - u) * iv;
            float n1 = (v[o8 * 8 + 1] - u) * iv;
            float n2 = (v[o8 * 8 + 2] - u) * iv;
            float n3 = (v[o8 * 8 + 3] - u) * iv;
            float n4 = (v[o8 * 8 + 4] - u) * iv;
            float n5 = (v[o8 * 8 + 5] - u) * iv;
            float n6 = (v[o8 * 8 + 6] - u) * iv;
            float n7 = (v[o8 * 8 + 7] - u) * iv;
            uint4 d;
            d.x = pack2(n0, n1);
            d.y = pack2(n2, n3);
            d.z = pack2(n4, n5);
            d.w = pack2(n6, n7);
            int byte = (rowoff + (q * 4 + o8) * 16) ^ swz;
            *reinterpret_cast<uint4*>(tb + byte) = d;
        }
    }
    __syncthreads();

    // ---- Phase 4: SWAPPED-operand MFMA: D[px][och] = mfma(A = n-x tile, B = W).
    //      Lane ends with 4 CONSECUTIVE PIXELS of ONE channel -> f32x4 nt store
    //      (nt removes the L2 write-allocate/RFO stall; measured -12 us vs cached). ----
    {
        const char* tb = (const char*)bufT;
        const int och  = (wv << 4) + (l & 15);      // lane's output channel
        const int prow = (l >> 4) << 2;             // px sub-row 0,4,8,12
        const int koff = (l >> 4) << 4;             // k-octet byte offset for A-read
        const float bb = bias[och];
        float* outp = out + base;
        #pragma unroll
        for (int pt = 0; pt < 8; ++pt) {
            const int ar   = (pt << 4) + (l & 15);
            const int aoff = ar * 256;
            const int aswz = (ar & 15) << 4;
            f32x4 acc = { bb, bb, bb, bb };
            #pragma unroll
            for (int kk = 0; kk < 4; ++kk) {
                int byte = (aoff + kk * 64 + koff) ^ aswz;
                bf16x8 afr = *reinterpret_cast<const bf16x8*>(tb + byte);
                acc = __builtin_amdgcn_mfma_f32_16x16x32_bf16(afr, wfrag[kk], acc, 0, 0, 0);
            }
            const int px0 = (pt << 4) + prow;       // 4 consecutive pixels
            float4 u4  = *reinterpret_cast<const float4*>(&u_s[px0]);
            float4 se4 = *reinterpret_cast<const float4*>(&se_s[px0]);
            float xr0, xr1, xr2, xr3;
            {
                int r0 = px0 + 0, r1 = px0 + 1, r2 = px0 + 2, r3 = px0 + 3;
                xr0 = bf2f(*reinterpret_cast<const unsigned short*>(tb + ((r0 * 256 + och * 2) ^ ((r0 & 15) << 4))));
                xr1 = bf2f(*reinterpret_cast<const unsigned short*>(tb + ((r1 * 256 + och * 2) ^ ((r1 & 15) << 4))));
                xr2 = bf2f(*reinterpret_cast<const unsigned short*>(tb + ((r2 * 256 + och * 2) ^ ((r2 & 15) << 4))));
                xr3 = bf2f(*reinterpret_cast<const unsigned short*>(tb + ((r3 * 256 + och * 2) ^ ((r3 & 15) << 4))));
            }
            f32x4 o4;
            o4[0] = fmaf(xr0, se4.x, u4.x) * acc[0];
            o4[1] = fmaf(xr1, se4.y, u4.y) * acc[1];
            o4[2] = fmaf(xr2, se4.z, u4.z) * acc[2];
            o4[3] = fmaf(xr3, se4.w, u4.w) * acc[3];
            __builtin_nontemporal_store(o4, reinterpret_cast<f32x4*>(outp + och * HW + px0));
        }
    }
}

extern "C" void kernel_launch(void* const* d_in, const int* in_sizes, int n_in,
                              void* d_out, int out_size, void* d_ws, size_t ws_size,
                              hipStream_t stream) {
    const float* x = (const float*)d_in[0];
    const float* W = (const float*)d_in[1];
    const float* b = (const float*)d_in[2];
    float* out     = (float*)d_out;

    const int nblk = 8 * HW / TILE;            // 4096 blocks
    spnorm_kernel<<<nblk, NT, 0, stream>>>(x, W, b, out);
}

// Round 19
// 106.355 us; speedup vs baseline: 1.1307x; 1.0056x over previous
//
#include <hip/hip_runtime.h>

#define EPS 1e-6f

constexpr int C    = 128;
constexpr int HW   = 65536;    // 256*256
constexpr int TILE = 128;      // pixels per block
constexpr int NT   = 512;      // 8 waves

typedef __attribute__((ext_vector_type(8))) short bf16x8;
typedef __attribute__((ext_vector_type(4))) float f32x4;

__device__ __forceinline__ unsigned short f2bf(float f) {   // RNE
    unsigned u = __float_as_uint(f);
    u += 0x7fff + ((u >> 16) & 1);
    return (unsigned short)(u >> 16);
}
__device__ __forceinline__ float bf2f(unsigned short u) {
    return __uint_as_float(((unsigned)u) << 16);
}
__device__ __forceinline__ unsigned pack2(float lo, float hi) {
    return (unsigned)f2bf(lo) | ((unsigned)f2bf(hi) << 16);
}

__global__ __launch_bounds__(NT, 4) void spnorm_kernel(
    const float* __restrict__ x, const float* __restrict__ W,
    const float* __restrict__ bias, float* __restrict__ out)
{
    // bufT[p][c]: normalized bf16, transposed, XOR-swizzled (byte ^= (p&15)<<4)
    __shared__ unsigned short bufT[C * TILE];              // 32 KB
    __shared__ float red1[4][TILE], red2[4][TILE];         // 4 KB
    __shared__ float u_s[TILE], se_s[TILE];                // 1 KB

    const int tid = threadIdx.x;
    const int l   = tid & 63;
    const int wv  = tid >> 6;
    const int batch = blockIdx.x >> 9;                     // 512 blocks per image
    const int hw0   = (blockIdx.x & 511) * TILE;
    const int base  = batch * (C * HW) + hw0;

    const int p = tid & 127;                               // pixel
    const int q = tid >> 7;                                // channel group (32 ch)

    // ---- Phase 1: x straight into registers, channel-strided, coalesced across p ----
    float v[32];
    {
        const float* xp = x + base + q * 32 * HW + p;
        #pragma unroll
        for (int i = 0; i < 32; ++i)
            v[i] = xp[i * HW];
    }

    // ---- W-fragments (fp32 -> bf16) from global; B operand of the swapped MFMA ----
    const int arow  = (wv << 4) + (l & 15);                // this lane's output channel row
    const int acol0 = (l >> 4) << 3;
    bf16x8 wfrag[4];
    #pragma unroll
    for (int kk = 0; kk < 4; ++kk) {
        const float* wp = W + arow * C + kk * 32 + acol0;
        float4 wa = *reinterpret_cast<const float4*>(wp);
        float4 wb = *reinterpret_cast<const float4*>(wp + 4);
        bf16x8 f;
        f[0] = (short)f2bf(wa.x); f[1] = (short)f2bf(wa.y);
        f[2] = (short)f2bf(wa.z); f[3] = (short)f2bf(wa.w);
        f[4] = (short)f2bf(wb.x); f[5] = (short)f2bf(wb.y);
        f[6] = (short)f2bf(wb.z); f[7] = (short)f2bf(wb.w);
        wfrag[kk] = f;
    }

    // ---- Phase 2: partial sums -> LDS ----
    {
        float s1 = 0.f, s2 = 0.f;
        #pragma unroll
        for (int i = 0; i < 32; ++i) {
            s1 += v[i];
            s2 = fmaf(v[i], v[i], s2);
        }
        red1[q][p] = s1;
        red2[q][p] = s2;
    }

    // Pin v[]: prevents reload-rematerialization across the barrier (rounds 8/10:
    // VGPR_Count=32 => compiler re-loads x in phase 3).
    #pragma unroll
    for (int i = 0; i < 32; ++i) asm volatile("" : "+v"(v[i]));

    __syncthreads();

    // ---- Phase 3: every thread finalizes (redundant x4), normalizes, writes bufT ----
    {
        float s1 = red1[0][p] + red1[1][p] + red1[2][p] + red1[3][p];
        float s2 = red2[0][p] + red2[1][p] + red2[2][p] + red2[3][p];
        float u   = s1 * (1.0f / 128.0f);
        float var = fmaxf((s2 - s1 * u) * (1.0f / 127.0f), 0.0f);
        float se  = sqrtf(var) + EPS;
        float iv  = 1.0f / se;
        if (q == 0) {                       // wave-uniform branch (tid < 128)
            u_s[p]  = u;
            se_s[p] = se;
        }
        char* tb = (char*)bufT;
        const int rowoff = p * 256;         // 128 ushort per row
        const int swz    = (p & 15) << 4;
        #pragma unroll
        for (int o8 = 0; o8 < 4; ++o8) {
            float n0 = (v[o8 * 8 + 0] - u) * iv;
            float n1 = (v[o8 * 8 + 1] - u) * iv;
            float n2 = (v[o8 * 8 + 2] - u) * iv;
            float n3 = (v[o8 * 8 + 3] - u) * iv;
            float n4 = (v[o8 * 8 + 4] - u) * iv;
            float n5 = (v[o8 * 8 + 5] - u) * iv;
            float n6 = (v[o8 * 8 + 6] - u) * iv;
            float n7 = (v[o8 * 8 + 7] - u) * iv;
            uint4 d;
            d.x = pack2(n0, n1);
            d.y = pack2(n2, n3);
            d.z = pack2(n4, n5);
            d.w = pack2(n6, n7);
            int byte = (rowoff + (q * 4 + o8) * 16) ^ swz;
            *reinterpret_cast<uint4*>(tb + byte) = d;
        }
    }
    __syncthreads();

    // ---- Phase 4: SWAPPED-operand MFMA, then epilogue, then ALL 8 nt stores
    //      BACK-TO-BACK (no intervening instrs) so the store coalescer sees both
    //      64 B halves of every 128 B output line adjacently and can merge. ----
    {
        const char* tb = (const char*)bufT;
        const int och  = (wv << 4) + (l & 15);      // lane's output channel
        const int prow = (l >> 4) << 2;             // px sub-row 0,4,8,12
        const int koff = (l >> 4) << 4;             // k-octet byte offset for A-read
        const float bb = bias[och];
        float* outp = out + base;

        // (a) all MFMAs
        f32x4 acc[8];
        #pragma unroll
        for (int pt = 0; pt < 8; ++pt) {
            const int ar   = (pt << 4) + (l & 15);
            const int aoff = ar * 256;
            const int aswz = (ar & 15) << 4;
            f32x4 a = { bb, bb, bb, bb };
            #pragma unroll
            for (int kk = 0; kk < 4; ++kk) {
                int byte = (aoff + kk * 64 + koff) ^ aswz;
                bf16x8 afr = *reinterpret_cast<const bf16x8*>(tb + byte);
                a = __builtin_amdgcn_mfma_f32_16x16x32_bf16(afr, wfrag[kk], a, 0, 0, 0);
            }
            acc[pt] = a;
        }

        // (b) all epilogue transforms (LDS reads + VALU), in place
        #pragma unroll
        for (int pt = 0; pt < 8; ++pt) {
            const int px0 = (pt << 4) + prow;
            float4 u4  = *reinterpret_cast<const float4*>(&u_s[px0]);
            float4 se4 = *reinterpret_cast<const float4*>(&se_s[px0]);
            int r0 = px0 + 0, r1 = px0 + 1, r2 = px0 + 2, r3 = px0 + 3;
            float xr0 = bf2f(*reinterpret_cast<const unsigned short*>(tb + ((r0 * 256 + och * 2) ^ ((r0 & 15) << 4))));
            float xr1 = bf2f(*reinterpret_cast<const unsigned short*>(tb + ((r1 * 256 + och * 2) ^ ((r1 & 15) << 4))));
            float xr2 = bf2f(*reinterpret_cast<const unsigned short*>(tb + ((r2 * 256 + och * 2) ^ ((r2 & 15) << 4))));
            float xr3 = bf2f(*reinterpret_cast<const unsigned short*>(tb + ((r3 * 256 + och * 2) ^ ((r3 & 15) << 4))));
            f32x4 o4;
            o4[0] = fmaf(xr0, se4.x, u4.x) * acc[pt][0];
            o4[1] = fmaf(xr1, se4.y, u4.y) * acc[pt][1];
            o4[2] = fmaf(xr2, se4.z, u4.z) * acc[pt][2];
            o4[3] = fmaf(xr3, se4.w, u4.w) * acc[pt][3];
            acc[pt] = o4;
        }

        // (c) 8 consecutive nt stores — px0 = pt*16+prow walks lines in order;
        //     pt pairs (0,1),(2,3).. cover each 128 B line's two halves adjacently.
        #pragma unroll
        for (int pt = 0; pt < 8; ++pt) {
            const int px0 = (pt << 4) + prow;
            __builtin_nontemporal_store(acc[pt], reinterpret_cast<f32x4*>(outp + och * HW + px0));
        }
    }
}

extern "C" void kernel_launch(void* const* d_in, const int* in_sizes, int n_in,
                              void* d_out, int out_size, void* d_ws, size_t ws_size,
                              hipStream_t stream) {
    const float* x = (const float*)d_in[0];
    const float* W = (const float*)d_in[1];
    const float* b = (const float*)d_in[2];
    float* out     = (float*)d_out;

    const int nblk = 8 * HW / TILE;            // 4096 blocks
    spnorm_kernel<<<nblk, NT, 0, stream>>>(x, W, b, out);
}